// Round 14
// baseline (246.965 us; speedup 1.0000x reference)
//
#include <hip/hip_runtime.h>
#include <hip/hip_bf16.h>

#define NUSER 100000
#define NGAME 20000
#define NTOT  120000   // NGAME + NUSER (games first in combined index space)
#define HDIM  128
#define NBUCK 469      // ceil(NTOT / 256) coarse buckets (dst >> 8)
#define CH    8192     // edges per stage-1 chunk

typedef short bf16x8 __attribute__((ext_vector_type(8)));
typedef float f32x4  __attribute__((ext_vector_type(4)));
typedef float f32x2  __attribute__((ext_vector_type(2)));

__device__ __forceinline__ unsigned short f2b(float f) {
  union { float f; unsigned u; } a;
  a.f = f;
  unsigned r = a.u + 0x7fff + ((a.u >> 16) & 1);  // RNE
  return (unsigned short)(r >> 16);
}
__device__ __forceinline__ float b2f_lo(unsigned u) {
  union { unsigned u; float f; } a; a.u = u << 16; return a.f;
}
__device__ __forceinline__ float b2f_hi(unsigned u) {
  union { unsigned u; float f; } a; a.u = u & 0xffff0000u; return a.f;
}

// ---------------------------------------------------------------------------
// repack: W[K][128] f32 -> fragment-ordered bf16 for mfma_f32_16x16x32_bf16
// ---------------------------------------------------------------------------
__global__ __launch_bounds__(256) void repack_kernel(
    const float* __restrict__ W0, const float* __restrict__ W1,
    const float* __restrict__ W2, const float* __restrict__ W3,
    const float* __restrict__ W4, const float* __restrict__ W5,
    unsigned short* __restrict__ P0, unsigned short* __restrict__ P1,
    unsigned short* __restrict__ P2, unsigned short* __restrict__ P3,
    unsigned short* __restrict__ P4, unsigned short* __restrict__ P5) {
  const float* W; unsigned short* P; int K;
  switch (blockIdx.y) {
    case 0: W = W0; P = P0; K = 64;  break;
    case 1: W = W1; P = P1; K = 128; break;
    case 2: W = W2; P = P2; K = 128; break;
    case 3: W = W3; P = P3; K = 128; break;
    case 4: W = W4; P = P4; K = 128; break;
    default: W = W5; P = P5; K = 128; break;
  }
  int t = blockIdx.x * 256 + threadIdx.x;
  int KT = K / 32;
  if (t >= KT * 8 * 64) return;
  int lane = t & 63;
  int nt = (t >> 6) & 7;
  int kt = t >> 9;
  int col = nt * 16 + (lane & 15);
  int krow = kt * 32 + (lane >> 4) * 8;
  unsigned short vals[8];
#pragma unroll
  for (int b = 0; b < 8; ++b) vals[b] = f2b(W[(size_t)(krow + b) * HDIM + col]);
  *reinterpret_cast<bf16x8*>(P + (size_t)t * 8) = *reinterpret_cast<bf16x8*>(vals);
}

// ---------------------------------------------------------------------------
// proj_mfma: h = relu(x @ W + b). If W8: also emit fp8(e4m3) copy h8 via
// LDS-staged coalesced writes (fused cvt8 pass).
// ---------------------------------------------------------------------------
template <int K, bool W8>
__global__ __launch_bounds__(256) void proj_mfma_kernel(
    const float* __restrict__ x, const unsigned short* __restrict__ Wp,
    const float* __restrict__ b, unsigned short* __restrict__ h,
    unsigned* __restrict__ h8, int M) {
  __shared__ __align__(16) unsigned char lds8[64 * 128];
  int l = threadIdx.x & 63;
  int wid = threadIdx.x >> 6;
  int r0 = blockIdx.x * 64 + wid * 16;
  int arow = r0 + (l & 15);
  if (arow >= M) arow = M - 1;
  const int KT = K / 32;
  f32x4 acc[8];
#pragma unroll
  for (int nt = 0; nt < 8; ++nt) acc[nt] = (f32x4){0.f, 0.f, 0.f, 0.f};
  const float* xr = x + (size_t)arow * K + (l >> 4) * 8;
  const bf16x8* Wf = (const bf16x8*)Wp;
#pragma unroll
  for (int kt = 0; kt < KT; ++kt) {
    float4 a0 = *(const float4*)(xr + kt * 32);
    float4 a1 = *(const float4*)(xr + kt * 32 + 4);
    bf16x8 af;
    af[0] = (short)f2b(a0.x); af[1] = (short)f2b(a0.y);
    af[2] = (short)f2b(a0.z); af[3] = (short)f2b(a0.w);
    af[4] = (short)f2b(a1.x); af[5] = (short)f2b(a1.y);
    af[6] = (short)f2b(a1.z); af[7] = (short)f2b(a1.w);
#pragma unroll
    for (int nt = 0; nt < 8; ++nt) {
      bf16x8 bf = Wf[(kt * 8 + nt) * 64 + l];
      acc[nt] = __builtin_amdgcn_mfma_f32_16x16x32_bf16(af, bf, acc[nt], 0, 0, 0);
    }
  }
  int rbase = r0 + ((l >> 4) << 2);
  int rtbase = wid * 16 + ((l >> 4) << 2);
#pragma unroll
  for (int nt = 0; nt < 8; ++nt) {
    int col = nt * 16 + (l & 15);
    float bias = b[col];
#pragma unroll
    for (int r = 0; r < 4; ++r) {
      int row = rbase + r;
      float v = fmaxf(acc[nt][r] + bias, 0.f);
      if (row < M) h[(size_t)row * HDIM + col] = f2b(v);
      if (W8) {
        unsigned t8 = __builtin_amdgcn_cvt_pk_fp8_f32(v, v, 0u, false);
        lds8[(rtbase + r) * 128 + col] = (unsigned char)(t8 & 0xFF);
      }
    }
  }
  if (W8) {
    __syncthreads();
    const uint4* src = (const uint4*)lds8;
    int blk0 = blockIdx.x * 64;
    for (int i = threadIdx.x; i < 512; i += 256) {  // 64 rows x 8 uint4
      int row = blk0 + (i >> 3);
      if (row < M) ((uint4*)h8)[(size_t)blockIdx.x * 512 + i] = src[i];
    }
  }
}

// ---------------------------------------------------------------------------
// out_mfma_fused: both relations in one launch. m/h row operands are
// single-touch -> nontemporal loads; out is write-once -> nontemporal store.
// Weights P stay cached (reused by every block).
// ---------------------------------------------------------------------------
#define GBK ((NGAME + 63) / 64)
#define UBK ((NUSER + 63) / 64)
__global__ __launch_bounds__(256) void out_mfma_fused_kernel(
    const unsigned short* __restrict__ m, const unsigned short* __restrict__ hg,
    const unsigned short* __restrict__ hu,
    const unsigned short* __restrict__ P_lug, const float* __restrict__ bl_ug,
    const unsigned short* __restrict__ P_rug,
    const unsigned short* __restrict__ P_lgu, const float* __restrict__ bl_gu,
    const unsigned short* __restrict__ P_rgu,
    float* __restrict__ out_game, float* __restrict__ out_user) {
  const unsigned short *mb, *h, *WlP, *WrP;
  const float* bl;
  float* out;
  int M, bi;
  if (blockIdx.x < GBK) {
    mb = m;                          h = hg; WlP = P_lug; bl = bl_ug; WrP = P_rug;
    out = out_game; M = NGAME; bi = blockIdx.x;
  } else {
    mb = m + (size_t)NGAME * HDIM;   h = hu; WlP = P_lgu; bl = bl_gu; WrP = P_rgu;
    out = out_user; M = NUSER; bi = blockIdx.x - GBK;
  }
  int l = threadIdx.x & 63;
  int wid = threadIdx.x >> 6;
  int r0 = bi * 64 + wid * 16;
  int arow = r0 + (l & 15);
  if (arow >= M) arow = M - 1;
  f32x4 acc[8];
#pragma unroll
  for (int nt = 0; nt < 8; ++nt) acc[nt] = (f32x4){0.f, 0.f, 0.f, 0.f};
  const unsigned short* mr = mb + (size_t)arow * HDIM + (l >> 4) * 8;
  const unsigned short* hr = h + (size_t)arow * HDIM + (l >> 4) * 8;
  const bf16x8* Wlf = (const bf16x8*)WlP;
  const bf16x8* Wrf = (const bf16x8*)WrP;
#pragma unroll
  for (int kt = 0; kt < 4; ++kt) {
    bf16x8 am = __builtin_nontemporal_load((const bf16x8*)(mr + kt * 32));
    bf16x8 ah = __builtin_nontemporal_load((const bf16x8*)(hr + kt * 32));
#pragma unroll
    for (int nt = 0; nt < 8; ++nt) {
      bf16x8 bl_f = Wlf[(kt * 8 + nt) * 64 + l];
      bf16x8 br_f = Wrf[(kt * 8 + nt) * 64 + l];
      acc[nt] = __builtin_amdgcn_mfma_f32_16x16x32_bf16(am, bl_f, acc[nt], 0, 0, 0);
      acc[nt] = __builtin_amdgcn_mfma_f32_16x16x32_bf16(ah, br_f, acc[nt], 0, 0, 0);
    }
  }
  int rbase = r0 + ((l >> 4) << 2);
#pragma unroll
  for (int nt = 0; nt < 8; ++nt) {
    int col = nt * 16 + (l & 15);
    float bias = bl[col];
#pragma unroll
    for (int r = 0; r < 4; ++r) {
      int row = rbase + r;
      if (row < M)
        __builtin_nontemporal_store(acc[nt][r] + bias, &out[(size_t)row * HDIM + col]);
    }
  }
}

// ---------------------------------------------------------------------------
// stage 1a: per-chunk LDS histogram over coarse buckets (dst>>8).
// ---------------------------------------------------------------------------
__global__ __launch_bounds__(256) void s1_hist_kernel(
    const int* __restrict__ dst_ug, const int* __restrict__ dst_gu,
    int* __restrict__ cnt, int E, int nch) {
  __shared__ int hist[NBUCK];
  for (int i = threadIdx.x; i < NBUCK; i += 256) hist[i] = 0;
  __syncthreads();
  int base = blockIdx.x * CH, endi = min(base + CH, 2 * E);
  for (int e = base + threadIdx.x; e < endi; e += 256) {
    int d = (e < E) ? dst_ug[e] : (NGAME + dst_gu[e - E]);
    atomicAdd(&hist[d >> 8], 1);
  }
  __syncthreads();
  for (int i = threadIdx.x; i < NBUCK; i += 256)
    cnt[i * nch + blockIdx.x] = hist[i];
}

// ---------------------------------------------------------------------------
// 2-phase exclusive scan (scan3 folded into consumers via bsum lookup)
// ---------------------------------------------------------------------------
__global__ __launch_bounds__(1024) void scan1_kernel(
    const int* __restrict__ cnt, int* __restrict__ off,
    int* __restrict__ bsum, int n) {
  __shared__ int wsum[16];
  int i = blockIdx.x * 1024 + threadIdx.x;
  int lane = threadIdx.x & 63, wid = threadIdx.x >> 6;
  int v = (i < n) ? cnt[i] : 0;
  int x = v;
#pragma unroll
  for (int d = 1; d < 64; d <<= 1) {
    int t = __shfl_up(x, (unsigned)d, 64);
    if (lane >= d) x += t;
  }
  if (lane == 63) wsum[wid] = x;
  __syncthreads();
  if (wid == 0 && lane < 16) {
    int w = wsum[lane];
#pragma unroll
    for (int d = 1; d < 16; d <<= 1) {
      int t = __shfl_up(w, (unsigned)d, 64);
      if (lane >= d) w += t;
    }
    wsum[lane] = w;
  }
  __syncthreads();
  int wavepre = (wid == 0) ? 0 : wsum[wid - 1];
  if (i < n) off[i] = wavepre + x - v;
  if (threadIdx.x == 1023) bsum[blockIdx.x] = wavepre + x;
}

__global__ __launch_bounds__(1024) void scan2_kernel(
    int* __restrict__ bsum, int* __restrict__ off, int nb, int n) {
  __shared__ int wsum[16];
  __shared__ int carry_s;
  int lane = threadIdx.x & 63, wid = threadIdx.x >> 6;
  if (threadIdx.x == 0) carry_s = 0;
  __syncthreads();
  for (int base = 0; base < nb; base += 1024) {
    int i = base + threadIdx.x;
    int v = (i < nb) ? bsum[i] : 0;
    int x = v;
#pragma unroll
    for (int d = 1; d < 64; d <<= 1) {
      int t = __shfl_up(x, (unsigned)d, 64);
      if (lane >= d) x += t;
    }
    if (lane == 63) wsum[wid] = x;
    __syncthreads();
    if (wid == 0 && lane < 16) {
      int w = wsum[lane];
#pragma unroll
      for (int d = 1; d < 16; d <<= 1) {
        int t = __shfl_up(w, (unsigned)d, 64);
        if (lane >= d) w += t;
      }
      wsum[lane] = w;
    }
    __syncthreads();
    int wavepre = (wid == 0) ? 0 : wsum[wid - 1];
    int carry = carry_s;
    if (i < nb) bsum[i] = carry + wavepre + x - v;  // exclusive
    __syncthreads();
    if (threadIdx.x == 1023) carry_s = carry + wsum[15];
    __syncthreads();
  }
  if (threadIdx.x == 0) off[n] = carry_s;  // grand total = 2E
}

// ---------------------------------------------------------------------------
// stage 1b: scatter packed (src<<8 | dst&255) into bucket-contiguous esort.
// Final offset = off[idx] + bsum[idx>>10] (scan3 folded in).
// ---------------------------------------------------------------------------
__global__ __launch_bounds__(256) void s1_scatter_kernel(
    const int* __restrict__ src_ug, const int* __restrict__ dst_ug,
    const int* __restrict__ src_gu, const int* __restrict__ dst_gu,
    const int* __restrict__ off, const int* __restrict__ bsum,
    unsigned* __restrict__ esort, int E, int nch) {
  __shared__ int bases[NBUCK];
  for (int i = threadIdx.x; i < NBUCK; i += 256) {
    int idx = i * nch + blockIdx.x;
    bases[i] = off[idx] + bsum[idx >> 10];
  }
  __syncthreads();
  int base = blockIdx.x * CH, endi = min(base + CH, 2 * E);
  for (int e = base + threadIdx.x; e < endi; e += 256) {
    int d, s;
    if (e < E) { d = dst_ug[e]; s = src_ug[e]; }
    else       { d = NGAME + dst_gu[e - E]; s = src_gu[e - E]; }
    int pos = atomicAdd(&bases[d >> 8], 1);
    esort[pos] = ((unsigned)s << 8) | (unsigned)(d & 255);
  }
}

// ---------------------------------------------------------------------------
// stage 2: per-bucket exact CSR via LDS histogram + scan. Zero global atomics.
// Bucket bounds = off[idx]+bsum[idx>>10] (scan3 folded in; idx==n -> off[n]).
// ---------------------------------------------------------------------------
__global__ __launch_bounds__(256) void s2_csr_kernel(
    const unsigned* __restrict__ esort, const int* __restrict__ off,
    const int* __restrict__ bsum, int* __restrict__ offd,
    int* __restrict__ esrc, int nch, int n) {
  __shared__ int hist[256], excl[256], run[256];
  __shared__ int wsum[4];
  int k = blockIdx.x;
  int tid = threadIdx.x;
  int idx0 = k * nch;
  int idx1 = (k + 1) * nch;
  int base = off[idx0] + bsum[idx0 >> 10];
  int end  = (idx1 < n) ? (off[idx1] + bsum[idx1 >> 10]) : off[n];
  hist[tid] = 0;
  run[tid] = 0;
  __syncthreads();
  for (int i = base + tid; i < end; i += 256)
    atomicAdd(&hist[esort[i] & 255], 1);
  __syncthreads();
  int lane = tid & 63, wid = tid >> 6;
  int v = hist[tid], x = v;
#pragma unroll
  for (int dd = 1; dd < 64; dd <<= 1) {
    int t = __shfl_up(x, (unsigned)dd, 64);
    if (lane >= dd) x += t;
  }
  if (lane == 63) wsum[wid] = x;
  __syncthreads();
  int wpre = 0;
  if (wid > 0) wpre += wsum[0];
  if (wid > 1) wpre += wsum[1];
  if (wid > 2) wpre += wsum[2];
  int ex = wpre + x - v;
  excl[tid] = ex;
  int d = k * 256 + tid;
  if (d <= NTOT) offd[d] = base + ex;
  __syncthreads();
  for (int i = base + tid; i < end; i += 256) {
    unsigned p = esort[i];
    int dl = p & 255;
    int pos = base + excl[dl] + atomicAdd(&run[dl], 1);
    esrc[pos] = (int)(p >> 8);
  }
}

// ---------------------------------------------------------------------------
// gather: one wave per dst row (120K waves of TLP). Game-dst rows read fp8
// hu8 (128B rows, 8 lanes/row, 16 edges in flight); user-dst rows read bf16
// hg (L2-hot, 16 lanes/row, 16 edges/iter).
// ---------------------------------------------------------------------------
#define ACC8(v)                         \
  do {                                  \
    acc[0] += b2f_lo((v).x);            \
    acc[1] += b2f_hi((v).x);            \
    acc[2] += b2f_lo((v).y);            \
    acc[3] += b2f_hi((v).y);            \
    acc[4] += b2f_lo((v).z);            \
    acc[5] += b2f_hi((v).z);            \
    acc[6] += b2f_lo((v).w);            \
    acc[7] += b2f_hi((v).w);            \
  } while (0)

#define ACCF8(v)                                                   \
  do {                                                             \
    f32x2 t;                                                       \
    t = __builtin_amdgcn_cvt_pk_f32_fp8((v).x, false);             \
    acc[0] += t[0]; acc[1] += t[1];                                \
    t = __builtin_amdgcn_cvt_pk_f32_fp8((v).x, true);              \
    acc[2] += t[0]; acc[3] += t[1];                                \
    t = __builtin_amdgcn_cvt_pk_f32_fp8((v).y, false);             \
    acc[4] += t[0]; acc[5] += t[1];                                \
    t = __builtin_amdgcn_cvt_pk_f32_fp8((v).y, true);              \
    acc[6] += t[0]; acc[7] += t[1];                                \
    t = __builtin_amdgcn_cvt_pk_f32_fp8((v).z, false);             \
    acc[8] += t[0]; acc[9] += t[1];                                \
    t = __builtin_amdgcn_cvt_pk_f32_fp8((v).z, true);              \
    acc[10] += t[0]; acc[11] += t[1];                              \
    t = __builtin_amdgcn_cvt_pk_f32_fp8((v).w, false);             \
    acc[12] += t[0]; acc[13] += t[1];                              \
    t = __builtin_amdgcn_cvt_pk_f32_fp8((v).w, true);              \
    acc[14] += t[0]; acc[15] += t[1];                              \
  } while (0)

__global__ __launch_bounds__(256) void gather_kernel(
    const unsigned* __restrict__ hu8, const unsigned short* __restrict__ hg,
    const int* __restrict__ esrc, const int* __restrict__ offd,
    unsigned short* __restrict__ m) {
  int w = (blockIdx.x * blockDim.x + threadIdx.x) >> 6;
  int lane = threadIdx.x & 63;
  if (w >= NTOT) return;
  int beg = offd[w], end = offd[w + 1];
  float inv = 1.f / fmaxf((float)(end - beg), 1.f);
  if (w < NGAME) {
    // ---- fp8 path: 8 lanes/row, 8 groups, 16 edges in flight ----
    int g = lane >> 3, c = lane & 7;
    const uint4* f = (const uint4*)hu8;  // row stride 8 uint4 (128 B)
    float acc[16];
#pragma unroll
    for (int i = 0; i < 16; ++i) acc[i] = 0.f;
    int k = beg + g;
    for (; k + 8 < end; k += 16) {
      int s0 = esrc[k];
      int s1 = esrc[k + 8];
      uint4 v0 = f[(size_t)s0 * 8 + c];
      uint4 v1 = f[(size_t)s1 * 8 + c];
      ACCF8(v0);
      ACCF8(v1);
    }
    {
      bool p0 = k < end, p1 = k + 8 < end;
      int a0 = p0 ? k : 0;
      int a1 = p1 ? k + 8 : 0;
      int s0 = esrc[a0];
      int s1 = esrc[a1];
      uint4 v0 = f[(size_t)s0 * 8 + c];
      uint4 v1 = f[(size_t)s1 * 8 + c];
      if (p0) ACCF8(v0);
      if (p1) ACCF8(v1);
    }
#pragma unroll
    for (int i = 0; i < 16; ++i) {
      acc[i] += __shfl_xor(acc[i], 8, 64);
      acc[i] += __shfl_xor(acc[i], 16, 64);
      acc[i] += __shfl_xor(acc[i], 32, 64);
    }
    unsigned o = (unsigned)f2b(acc[2 * g] * inv) |
                 ((unsigned)f2b(acc[2 * g + 1] * inv) << 16);
    ((unsigned*)m)[(size_t)w * 64 + c * 8 + g] = o;
  } else {
    // ---- bf16 path: 16 lanes/row, 4 groups, 16 edges/iter ----
    int g = lane >> 4, c = lane & 15;
    const uint4* f = (const uint4*)hg;  // row stride 16 uint4 (256 B)
    float acc[8];
#pragma unroll
    for (int i = 0; i < 8; ++i) acc[i] = 0.f;
    int k = beg + g;
    for (; k + 12 < end; k += 16) {
      int s0 = esrc[k];
      int s1 = esrc[k + 4];
      int s2 = esrc[k + 8];
      int s3 = esrc[k + 12];
      uint4 v0 = f[(size_t)s0 * 16 + c];
      uint4 v1 = f[(size_t)s1 * 16 + c];
      uint4 v2 = f[(size_t)s2 * 16 + c];
      uint4 v3 = f[(size_t)s3 * 16 + c];
      ACC8(v0);
      ACC8(v1);
      ACC8(v2);
      ACC8(v3);
    }
    {
      int k0 = k, k1 = k + 4, k2 = k + 8;
      bool p0 = k0 < end, p1 = k1 < end, p2 = k2 < end;
      int a0 = p0 ? k0 : 0;
      int a1 = p1 ? k1 : 0;
      int a2 = p2 ? k2 : 0;
      int s0 = esrc[a0];
      int s1 = esrc[a1];
      int s2 = esrc[a2];
      uint4 v0 = f[(size_t)s0 * 16 + c];
      uint4 v1 = f[(size_t)s1 * 16 + c];
      uint4 v2 = f[(size_t)s2 * 16 + c];
      if (p0) ACC8(v0);
      if (p1) ACC8(v1);
      if (p2) ACC8(v2);
    }
#pragma unroll
    for (int i = 0; i < 8; ++i) {
      acc[i] += __shfl_xor(acc[i], 16, 64);
      acc[i] += __shfl_xor(acc[i], 32, 64);
    }
    unsigned o = (unsigned)f2b(acc[2 * g] * inv) |
                 ((unsigned)f2b(acc[2 * g + 1] * inv) << 16);
    ((unsigned*)m)[(size_t)w * 64 + c * 4 + g] = o;
  }
}

extern "C" void kernel_launch(void* const* d_in, const int* in_sizes, int n_in,
                              void* d_out, int out_size, void* d_ws, size_t ws_size,
                              hipStream_t stream) {
  const float* x_user = (const float*)d_in[0];
  const float* x_game = (const float*)d_in[1];
  const float* W_user = (const float*)d_in[2];
  const float* b_user = (const float*)d_in[3];
  const float* W_game = (const float*)d_in[4];
  const float* b_game = (const float*)d_in[5];
  const float* Wl_ug  = (const float*)d_in[6];
  const float* bl_ug  = (const float*)d_in[7];
  const float* Wr_ug  = (const float*)d_in[8];
  const float* Wl_gu  = (const float*)d_in[9];
  const float* bl_gu  = (const float*)d_in[10];
  const float* Wr_gu  = (const float*)d_in[11];
  const int*   src_ug = (const int*)d_in[12];
  const int*   dst_ug = (const int*)d_in[13];
  const int*   src_gu = (const int*)d_in[14];
  const int*   dst_gu = (const int*)d_in[15];
  const int E = in_sizes[12];

  const int nch = (2 * E + CH - 1) / CH;      // stage-1 chunks
  const int n   = NBUCK * nch;                // scan length
  const int nb  = (n + 1023) / 1024;

  // workspace carve
  char* ws = (char*)d_ws;
  unsigned short* hu  = (unsigned short*)ws; ws += (size_t)NUSER * HDIM * 2;  // 25.6 MB
  unsigned short* hg  = (unsigned short*)ws; ws += (size_t)NGAME * HDIM * 2;  // 5.12 MB
  unsigned short* m   = (unsigned short*)ws; ws += (size_t)NTOT * HDIM * 2;   // 30.7 MB
  unsigned* hu8 = (unsigned*)ws; ws += (size_t)NUSER * HDIM;                   // 12.8 MB
  unsigned* esort = (unsigned*)ws; ws += (size_t)2 * E * 4;                    // 12.8 MB
  int* esrc  = (int*)ws; ws += (size_t)2 * E * 4;                              // 12.8 MB
  int* cnt   = (int*)ws; ws += (size_t)n * 4;                                  // ~0.75 MB
  int* off   = (int*)ws; ws += (size_t)(n + 1) * 4;
  int* offd  = (int*)ws; ws += (size_t)(NTOT + 1) * 4;                         // 0.48 MB
  int* bsum  = (int*)ws; ws += 2048 * 4;
  unsigned short* P_wu  = (unsigned short*)ws; ws += (size_t)2 * 8 * 64 * 8 * 2;  // 16 KB
  unsigned short* P_wg  = (unsigned short*)ws; ws += (size_t)4 * 8 * 64 * 8 * 2;  // 32 KB
  unsigned short* P_lug = (unsigned short*)ws; ws += (size_t)4 * 8 * 64 * 8 * 2;
  unsigned short* P_rug = (unsigned short*)ws; ws += (size_t)4 * 8 * 64 * 8 * 2;
  unsigned short* P_lgu = (unsigned short*)ws; ws += (size_t)4 * 8 * 64 * 8 * 2;
  unsigned short* P_rgu = (unsigned short*)ws; ws += (size_t)4 * 8 * 64 * 8 * 2;

  float* out_user = (float*)d_out;
  float* out_game = (float*)d_out + (size_t)NUSER * HDIM;

  // one-shot weight repack to MFMA fragment order (bf16)
  repack_kernel<<<dim3(8, 6), 256, 0, stream>>>(
      W_user, W_game, Wl_ug, Wr_ug, Wl_gu, Wr_gu,
      P_wu, P_wg, P_lug, P_rug, P_lgu, P_rgu);

  // input projections + relu (user proj also emits fp8 copy hu8)
  proj_mfma_kernel<64, true><<<(NUSER + 63) / 64, 256, 0, stream>>>(
      x_user, P_wu, b_user, hu, hu8, NUSER);
  proj_mfma_kernel<128, false><<<(NGAME + 63) / 64, 256, 0, stream>>>(
      x_game, P_wg, b_game, hg, nullptr, NGAME);

  // two-level counting sort (zero global atomics; scan3 folded into consumers)
  s1_hist_kernel<<<nch, 256, 0, stream>>>(dst_ug, dst_gu, cnt, E, nch);
  scan1_kernel<<<nb, 1024, 0, stream>>>(cnt, off, bsum, n);
  scan2_kernel<<<1, 1024, 0, stream>>>(bsum, off, nb, n);
  s1_scatter_kernel<<<nch, 256, 0, stream>>>(src_ug, dst_ug, src_gu, dst_gu, off, bsum, esort, E, nch);
  s2_csr_kernel<<<NBUCK, 256, 0, stream>>>(esort, off, bsum, offd, esrc, nch, n);

  // combined gather (means for both relations; one wave per row)
  gather_kernel<<<(NTOT * 64 + 255) / 256, 256, 0, stream>>>(hu8, hg, esrc, offd, m);

  // fused output projections
  out_mfma_fused_kernel<<<GBK + UBK, 256, 0, stream>>>(
      m, hg, hu, P_lug, bl_ug, P_rug, P_lgu, bl_gu, P_rgu, out_game, out_user);
}

// Round 15
// 230.297 us; speedup vs baseline: 1.0724x; 1.0724x over previous
//
#include <hip/hip_runtime.h>
#include <hip/hip_bf16.h>

#define NUSER 100000
#define NGAME 20000
#define NTOT  120000   // NGAME + NUSER (games first in combined index space)
#define HDIM  128
#define NBUCK 469      // ceil(NTOT / 256) coarse buckets (dst >> 8)
#define CH    8192     // edges per stage-1 chunk

typedef short bf16x8 __attribute__((ext_vector_type(8)));
typedef float f32x4  __attribute__((ext_vector_type(4)));
typedef float f32x2  __attribute__((ext_vector_type(2)));

__device__ __forceinline__ unsigned short f2b(float f) {
  union { float f; unsigned u; } a;
  a.f = f;
  unsigned r = a.u + 0x7fff + ((a.u >> 16) & 1);  // RNE
  return (unsigned short)(r >> 16);
}
__device__ __forceinline__ float b2f_lo(unsigned u) {
  union { unsigned u; float f; } a; a.u = u << 16; return a.f;
}
__device__ __forceinline__ float b2f_hi(unsigned u) {
  union { unsigned u; float f; } a; a.u = u & 0xffff0000u; return a.f;
}

// ---------------------------------------------------------------------------
// repack: W[K][128] f32 -> fragment-ordered bf16 for mfma_f32_16x16x32_bf16
// ---------------------------------------------------------------------------
__global__ __launch_bounds__(256) void repack_kernel(
    const float* __restrict__ W0, const float* __restrict__ W1,
    const float* __restrict__ W2, const float* __restrict__ W3,
    const float* __restrict__ W4, const float* __restrict__ W5,
    unsigned short* __restrict__ P0, unsigned short* __restrict__ P1,
    unsigned short* __restrict__ P2, unsigned short* __restrict__ P3,
    unsigned short* __restrict__ P4, unsigned short* __restrict__ P5) {
  const float* W; unsigned short* P; int K;
  switch (blockIdx.y) {
    case 0: W = W0; P = P0; K = 64;  break;
    case 1: W = W1; P = P1; K = 128; break;
    case 2: W = W2; P = P2; K = 128; break;
    case 3: W = W3; P = P3; K = 128; break;
    case 4: W = W4; P = P4; K = 128; break;
    default: W = W5; P = P5; K = 128; break;
  }
  int t = blockIdx.x * 256 + threadIdx.x;
  int KT = K / 32;
  if (t >= KT * 8 * 64) return;
  int lane = t & 63;
  int nt = (t >> 6) & 7;
  int kt = t >> 9;
  int col = nt * 16 + (lane & 15);
  int krow = kt * 32 + (lane >> 4) * 8;
  unsigned short vals[8];
#pragma unroll
  for (int b = 0; b < 8; ++b) vals[b] = f2b(W[(size_t)(krow + b) * HDIM + col]);
  *reinterpret_cast<bf16x8*>(P + (size_t)t * 8) = *reinterpret_cast<bf16x8*>(vals);
}

// ---------------------------------------------------------------------------
// proj_mfma: h = relu(x @ W + b). If W8: also emit fp8(e4m3) copy h8 via
// LDS-staged coalesced writes (fused cvt8 pass).
// ---------------------------------------------------------------------------
template <int K, bool W8>
__global__ __launch_bounds__(256) void proj_mfma_kernel(
    const float* __restrict__ x, const unsigned short* __restrict__ Wp,
    const float* __restrict__ b, unsigned short* __restrict__ h,
    unsigned* __restrict__ h8, int M) {
  __shared__ __align__(16) unsigned char lds8[64 * 128];
  int l = threadIdx.x & 63;
  int wid = threadIdx.x >> 6;
  int r0 = blockIdx.x * 64 + wid * 16;
  int arow = r0 + (l & 15);
  if (arow >= M) arow = M - 1;
  const int KT = K / 32;
  f32x4 acc[8];
#pragma unroll
  for (int nt = 0; nt < 8; ++nt) acc[nt] = (f32x4){0.f, 0.f, 0.f, 0.f};
  const float* xr = x + (size_t)arow * K + (l >> 4) * 8;
  const bf16x8* Wf = (const bf16x8*)Wp;
#pragma unroll
  for (int kt = 0; kt < KT; ++kt) {
    float4 a0 = *(const float4*)(xr + kt * 32);
    float4 a1 = *(const float4*)(xr + kt * 32 + 4);
    bf16x8 af;
    af[0] = (short)f2b(a0.x); af[1] = (short)f2b(a0.y);
    af[2] = (short)f2b(a0.z); af[3] = (short)f2b(a0.w);
    af[4] = (short)f2b(a1.x); af[5] = (short)f2b(a1.y);
    af[6] = (short)f2b(a1.z); af[7] = (short)f2b(a1.w);
#pragma unroll
    for (int nt = 0; nt < 8; ++nt) {
      bf16x8 bf = Wf[(kt * 8 + nt) * 64 + l];
      acc[nt] = __builtin_amdgcn_mfma_f32_16x16x32_bf16(af, bf, acc[nt], 0, 0, 0);
    }
  }
  int rbase = r0 + ((l >> 4) << 2);
  int rtbase = wid * 16 + ((l >> 4) << 2);
#pragma unroll
  for (int nt = 0; nt < 8; ++nt) {
    int col = nt * 16 + (l & 15);
    float bias = b[col];
#pragma unroll
    for (int r = 0; r < 4; ++r) {
      int row = rbase + r;
      float v = fmaxf(acc[nt][r] + bias, 0.f);
      if (row < M) h[(size_t)row * HDIM + col] = f2b(v);
      if (W8) {
        unsigned t8 = __builtin_amdgcn_cvt_pk_fp8_f32(v, v, 0u, false);
        lds8[(rtbase + r) * 128 + col] = (unsigned char)(t8 & 0xFF);
      }
    }
  }
  if (W8) {
    __syncthreads();
    const uint4* src = (const uint4*)lds8;
    int blk0 = blockIdx.x * 64;
    for (int i = threadIdx.x; i < 512; i += 256) {  // 64 rows x 8 uint4
      int row = blk0 + (i >> 3);
      if (row < M) ((uint4*)h8)[(size_t)blockIdx.x * 512 + i] = src[i];
    }
  }
}

// ---------------------------------------------------------------------------
// out_mfma_fused: both relations in one launch (plain loads/stores; m and h
// are L2-warm from the gather — NT hints here regressed, round 14).
// ---------------------------------------------------------------------------
#define GBK ((NGAME + 63) / 64)
#define UBK ((NUSER + 63) / 64)
__global__ __launch_bounds__(256) void out_mfma_fused_kernel(
    const unsigned short* __restrict__ m, const unsigned short* __restrict__ hg,
    const unsigned short* __restrict__ hu,
    const unsigned short* __restrict__ P_lug, const float* __restrict__ bl_ug,
    const unsigned short* __restrict__ P_rug,
    const unsigned short* __restrict__ P_lgu, const float* __restrict__ bl_gu,
    const unsigned short* __restrict__ P_rgu,
    float* __restrict__ out_game, float* __restrict__ out_user) {
  const unsigned short *mb, *h, *WlP, *WrP;
  const float* bl;
  float* out;
  int M, bi;
  if (blockIdx.x < GBK) {
    mb = m;                          h = hg; WlP = P_lug; bl = bl_ug; WrP = P_rug;
    out = out_game; M = NGAME; bi = blockIdx.x;
  } else {
    mb = m + (size_t)NGAME * HDIM;   h = hu; WlP = P_lgu; bl = bl_gu; WrP = P_rgu;
    out = out_user; M = NUSER; bi = blockIdx.x - GBK;
  }
  int l = threadIdx.x & 63;
  int wid = threadIdx.x >> 6;
  int r0 = bi * 64 + wid * 16;
  int arow = r0 + (l & 15);
  if (arow >= M) arow = M - 1;
  f32x4 acc[8];
#pragma unroll
  for (int nt = 0; nt < 8; ++nt) acc[nt] = (f32x4){0.f, 0.f, 0.f, 0.f};
  const unsigned short* mr = mb + (size_t)arow * HDIM + (l >> 4) * 8;
  const unsigned short* hr = h + (size_t)arow * HDIM + (l >> 4) * 8;
  const bf16x8* Wlf = (const bf16x8*)WlP;
  const bf16x8* Wrf = (const bf16x8*)WrP;
#pragma unroll
  for (int kt = 0; kt < 4; ++kt) {
    bf16x8 am = *(const bf16x8*)(mr + kt * 32);
    bf16x8 ah = *(const bf16x8*)(hr + kt * 32);
#pragma unroll
    for (int nt = 0; nt < 8; ++nt) {
      bf16x8 bl_f = Wlf[(kt * 8 + nt) * 64 + l];
      bf16x8 br_f = Wrf[(kt * 8 + nt) * 64 + l];
      acc[nt] = __builtin_amdgcn_mfma_f32_16x16x32_bf16(am, bl_f, acc[nt], 0, 0, 0);
      acc[nt] = __builtin_amdgcn_mfma_f32_16x16x32_bf16(ah, br_f, acc[nt], 0, 0, 0);
    }
  }
  int rbase = r0 + ((l >> 4) << 2);
#pragma unroll
  for (int nt = 0; nt < 8; ++nt) {
    int col = nt * 16 + (l & 15);
    float bias = bl[col];
#pragma unroll
    for (int r = 0; r < 4; ++r) {
      int row = rbase + r;
      if (row < M) out[(size_t)row * HDIM + col] = acc[nt][r] + bias;
    }
  }
}

// ---------------------------------------------------------------------------
// stage 1a: per-chunk LDS histogram over coarse buckets (dst>>8).
// ---------------------------------------------------------------------------
__global__ __launch_bounds__(256) void s1_hist_kernel(
    const int* __restrict__ dst_ug, const int* __restrict__ dst_gu,
    int* __restrict__ cnt, int E, int nch) {
  __shared__ int hist[NBUCK];
  for (int i = threadIdx.x; i < NBUCK; i += 256) hist[i] = 0;
  __syncthreads();
  int base = blockIdx.x * CH, endi = min(base + CH, 2 * E);
  for (int e = base + threadIdx.x; e < endi; e += 256) {
    int d = (e < E) ? dst_ug[e] : (NGAME + dst_gu[e - E]);
    atomicAdd(&hist[d >> 8], 1);
  }
  __syncthreads();
  for (int i = threadIdx.x; i < NBUCK; i += 256)
    cnt[i * nch + blockIdx.x] = hist[i];
}

// ---------------------------------------------------------------------------
// 2-phase exclusive scan (scan3 folded into consumers via bsum lookup)
// ---------------------------------------------------------------------------
__global__ __launch_bounds__(1024) void scan1_kernel(
    const int* __restrict__ cnt, int* __restrict__ off,
    int* __restrict__ bsum, int n) {
  __shared__ int wsum[16];
  int i = blockIdx.x * 1024 + threadIdx.x;
  int lane = threadIdx.x & 63, wid = threadIdx.x >> 6;
  int v = (i < n) ? cnt[i] : 0;
  int x = v;
#pragma unroll
  for (int d = 1; d < 64; d <<= 1) {
    int t = __shfl_up(x, (unsigned)d, 64);
    if (lane >= d) x += t;
  }
  if (lane == 63) wsum[wid] = x;
  __syncthreads();
  if (wid == 0 && lane < 16) {
    int w = wsum[lane];
#pragma unroll
    for (int d = 1; d < 16; d <<= 1) {
      int t = __shfl_up(w, (unsigned)d, 64);
      if (lane >= d) w += t;
    }
    wsum[lane] = w;
  }
  __syncthreads();
  int wavepre = (wid == 0) ? 0 : wsum[wid - 1];
  if (i < n) off[i] = wavepre + x - v;
  if (threadIdx.x == 1023) bsum[blockIdx.x] = wavepre + x;
}

__global__ __launch_bounds__(1024) void scan2_kernel(
    int* __restrict__ bsum, int* __restrict__ off, int nb, int n) {
  __shared__ int wsum[16];
  __shared__ int carry_s;
  int lane = threadIdx.x & 63, wid = threadIdx.x >> 6;
  if (threadIdx.x == 0) carry_s = 0;
  __syncthreads();
  for (int base = 0; base < nb; base += 1024) {
    int i = base + threadIdx.x;
    int v = (i < nb) ? bsum[i] : 0;
    int x = v;
#pragma unroll
    for (int d = 1; d < 64; d <<= 1) {
      int t = __shfl_up(x, (unsigned)d, 64);
      if (lane >= d) x += t;
    }
    if (lane == 63) wsum[wid] = x;
    __syncthreads();
    if (wid == 0 && lane < 16) {
      int w = wsum[lane];
#pragma unroll
      for (int d = 1; d < 16; d <<= 1) {
        int t = __shfl_up(w, (unsigned)d, 64);
        if (lane >= d) w += t;
      }
      wsum[lane] = w;
    }
    __syncthreads();
    int wavepre = (wid == 0) ? 0 : wsum[wid - 1];
    int carry = carry_s;
    if (i < nb) bsum[i] = carry + wavepre + x - v;  // exclusive
    __syncthreads();
    if (threadIdx.x == 1023) carry_s = carry + wsum[15];
    __syncthreads();
  }
  if (threadIdx.x == 0) off[n] = carry_s;  // grand total = 2E
}

// ---------------------------------------------------------------------------
// stage 1b: scatter packed (src<<8 | dst&255) into bucket-contiguous esort.
// Final offset = off[idx] + bsum[idx>>10] (scan3 folded in).
// ---------------------------------------------------------------------------
__global__ __launch_bounds__(256) void s1_scatter_kernel(
    const int* __restrict__ src_ug, const int* __restrict__ dst_ug,
    const int* __restrict__ src_gu, const int* __restrict__ dst_gu,
    const int* __restrict__ off, const int* __restrict__ bsum,
    unsigned* __restrict__ esort, int E, int nch) {
  __shared__ int bases[NBUCK];
  for (int i = threadIdx.x; i < NBUCK; i += 256) {
    int idx = i * nch + blockIdx.x;
    bases[i] = off[idx] + bsum[idx >> 10];
  }
  __syncthreads();
  int base = blockIdx.x * CH, endi = min(base + CH, 2 * E);
  for (int e = base + threadIdx.x; e < endi; e += 256) {
    int d, s;
    if (e < E) { d = dst_ug[e]; s = src_ug[e]; }
    else       { d = NGAME + dst_gu[e - E]; s = src_gu[e - E]; }
    int pos = atomicAdd(&bases[d >> 8], 1);
    esort[pos] = ((unsigned)s << 8) | (unsigned)(d & 255);
  }
}

// ---------------------------------------------------------------------------
// stage 2: per-bucket exact CSR via LDS histogram + scan. Zero global atomics.
// Bucket bounds = off[idx]+bsum[idx>>10] (scan3 folded in; idx==n -> off[n]).
// ---------------------------------------------------------------------------
__global__ __launch_bounds__(256) void s2_csr_kernel(
    const unsigned* __restrict__ esort, const int* __restrict__ off,
    const int* __restrict__ bsum, int* __restrict__ offd,
    int* __restrict__ esrc, int nch, int n) {
  __shared__ int hist[256], excl[256], run[256];
  __shared__ int wsum[4];
  int k = blockIdx.x;
  int tid = threadIdx.x;
  int idx0 = k * nch;
  int idx1 = (k + 1) * nch;
  int base = off[idx0] + bsum[idx0 >> 10];
  int end  = (idx1 < n) ? (off[idx1] + bsum[idx1 >> 10]) : off[n];
  hist[tid] = 0;
  run[tid] = 0;
  __syncthreads();
  for (int i = base + tid; i < end; i += 256)
    atomicAdd(&hist[esort[i] & 255], 1);
  __syncthreads();
  int lane = tid & 63, wid = tid >> 6;
  int v = hist[tid], x = v;
#pragma unroll
  for (int dd = 1; dd < 64; dd <<= 1) {
    int t = __shfl_up(x, (unsigned)dd, 64);
    if (lane >= dd) x += t;
  }
  if (lane == 63) wsum[wid] = x;
  __syncthreads();
  int wpre = 0;
  if (wid > 0) wpre += wsum[0];
  if (wid > 1) wpre += wsum[1];
  if (wid > 2) wpre += wsum[2];
  int ex = wpre + x - v;
  excl[tid] = ex;
  int d = k * 256 + tid;
  if (d <= NTOT) offd[d] = base + ex;
  __syncthreads();
  for (int i = base + tid; i < end; i += 256) {
    unsigned p = esort[i];
    int dl = p & 255;
    int pos = base + excl[dl] + atomicAdd(&run[dl], 1);
    esrc[pos] = (int)(p >> 8);
  }
}

// ---------------------------------------------------------------------------
// gather: one wave per dst row (120K waves of TLP). Game-dst rows read fp8
// hu8 (128B rows, 8 lanes/row, 16 edges in flight); user-dst rows read bf16
// hg (L2-hot, 16 lanes/row, 16 edges/iter).
// ---------------------------------------------------------------------------
#define ACC8(v)                         \
  do {                                  \
    acc[0] += b2f_lo((v).x);            \
    acc[1] += b2f_hi((v).x);            \
    acc[2] += b2f_lo((v).y);            \
    acc[3] += b2f_hi((v).y);            \
    acc[4] += b2f_lo((v).z);            \
    acc[5] += b2f_hi((v).z);            \
    acc[6] += b2f_lo((v).w);            \
    acc[7] += b2f_hi((v).w);            \
  } while (0)

#define ACCF8(v)                                                   \
  do {                                                             \
    f32x2 t;                                                       \
    t = __builtin_amdgcn_cvt_pk_f32_fp8((v).x, false);             \
    acc[0] += t[0]; acc[1] += t[1];                                \
    t = __builtin_amdgcn_cvt_pk_f32_fp8((v).x, true);              \
    acc[2] += t[0]; acc[3] += t[1];                                \
    t = __builtin_amdgcn_cvt_pk_f32_fp8((v).y, false);             \
    acc[4] += t[0]; acc[5] += t[1];                                \
    t = __builtin_amdgcn_cvt_pk_f32_fp8((v).y, true);              \
    acc[6] += t[0]; acc[7] += t[1];                                \
    t = __builtin_amdgcn_cvt_pk_f32_fp8((v).z, false);             \
    acc[8] += t[0]; acc[9] += t[1];                                \
    t = __builtin_amdgcn_cvt_pk_f32_fp8((v).z, true);              \
    acc[10] += t[0]; acc[11] += t[1];                              \
    t = __builtin_amdgcn_cvt_pk_f32_fp8((v).w, false);             \
    acc[12] += t[0]; acc[13] += t[1];                              \
    t = __builtin_amdgcn_cvt_pk_f32_fp8((v).w, true);              \
    acc[14] += t[0]; acc[15] += t[1];                              \
  } while (0)

__global__ __launch_bounds__(256) void gather_kernel(
    const unsigned* __restrict__ hu8, const unsigned short* __restrict__ hg,
    const int* __restrict__ esrc, const int* __restrict__ offd,
    unsigned short* __restrict__ m) {
  int w = (blockIdx.x * blockDim.x + threadIdx.x) >> 6;
  int lane = threadIdx.x & 63;
  if (w >= NTOT) return;
  int beg = offd[w], end = offd[w + 1];
  float inv = 1.f / fmaxf((float)(end - beg), 1.f);
  if (w < NGAME) {
    // ---- fp8 path: 8 lanes/row, 8 groups, 16 edges in flight ----
    int g = lane >> 3, c = lane & 7;
    const uint4* f = (const uint4*)hu8;  // row stride 8 uint4 (128 B)
    float acc[16];
#pragma unroll
    for (int i = 0; i < 16; ++i) acc[i] = 0.f;
    int k = beg + g;
    for (; k + 8 < end; k += 16) {
      int s0 = esrc[k];
      int s1 = esrc[k + 8];
      uint4 v0 = f[(size_t)s0 * 8 + c];
      uint4 v1 = f[(size_t)s1 * 8 + c];
      ACCF8(v0);
      ACCF8(v1);
    }
    {
      bool p0 = k < end, p1 = k + 8 < end;
      int a0 = p0 ? k : 0;
      int a1 = p1 ? k + 8 : 0;
      int s0 = esrc[a0];
      int s1 = esrc[a1];
      uint4 v0 = f[(size_t)s0 * 8 + c];
      uint4 v1 = f[(size_t)s1 * 8 + c];
      if (p0) ACCF8(v0);
      if (p1) ACCF8(v1);
    }
#pragma unroll
    for (int i = 0; i < 16; ++i) {
      acc[i] += __shfl_xor(acc[i], 8, 64);
      acc[i] += __shfl_xor(acc[i], 16, 64);
      acc[i] += __shfl_xor(acc[i], 32, 64);
    }
    unsigned o = (unsigned)f2b(acc[2 * g] * inv) |
                 ((unsigned)f2b(acc[2 * g + 1] * inv) << 16);
    ((unsigned*)m)[(size_t)w * 64 + c * 8 + g] = o;
  } else {
    // ---- bf16 path: 16 lanes/row, 4 groups, 16 edges/iter ----
    int g = lane >> 4, c = lane & 15;
    const uint4* f = (const uint4*)hg;  // row stride 16 uint4 (256 B)
    float acc[8];
#pragma unroll
    for (int i = 0; i < 8; ++i) acc[i] = 0.f;
    int k = beg + g;
    for (; k + 12 < end; k += 16) {
      int s0 = esrc[k];
      int s1 = esrc[k + 4];
      int s2 = esrc[k + 8];
      int s3 = esrc[k + 12];
      uint4 v0 = f[(size_t)s0 * 16 + c];
      uint4 v1 = f[(size_t)s1 * 16 + c];
      uint4 v2 = f[(size_t)s2 * 16 + c];
      uint4 v3 = f[(size_t)s3 * 16 + c];
      ACC8(v0);
      ACC8(v1);
      ACC8(v2);
      ACC8(v3);
    }
    {
      int k0 = k, k1 = k + 4, k2 = k + 8;
      bool p0 = k0 < end, p1 = k1 < end, p2 = k2 < end;
      int a0 = p0 ? k0 : 0;
      int a1 = p1 ? k1 : 0;
      int a2 = p2 ? k2 : 0;
      int s0 = esrc[a0];
      int s1 = esrc[a1];
      int s2 = esrc[a2];
      uint4 v0 = f[(size_t)s0 * 16 + c];
      uint4 v1 = f[(size_t)s1 * 16 + c];
      uint4 v2 = f[(size_t)s2 * 16 + c];
      if (p0) ACC8(v0);
      if (p1) ACC8(v1);
      if (p2) ACC8(v2);
    }
#pragma unroll
    for (int i = 0; i < 8; ++i) {
      acc[i] += __shfl_xor(acc[i], 16, 64);
      acc[i] += __shfl_xor(acc[i], 32, 64);
    }
    unsigned o = (unsigned)f2b(acc[2 * g] * inv) |
                 ((unsigned)f2b(acc[2 * g + 1] * inv) << 16);
    ((unsigned*)m)[(size_t)w * 64 + c * 4 + g] = o;
  }
}

extern "C" void kernel_launch(void* const* d_in, const int* in_sizes, int n_in,
                              void* d_out, int out_size, void* d_ws, size_t ws_size,
                              hipStream_t stream) {
  const float* x_user = (const float*)d_in[0];
  const float* x_game = (const float*)d_in[1];
  const float* W_user = (const float*)d_in[2];
  const float* b_user = (const float*)d_in[3];
  const float* W_game = (const float*)d_in[4];
  const float* b_game = (const float*)d_in[5];
  const float* Wl_ug  = (const float*)d_in[6];
  const float* bl_ug  = (const float*)d_in[7];
  const float* Wr_ug  = (const float*)d_in[8];
  const float* Wl_gu  = (const float*)d_in[9];
  const float* bl_gu  = (const float*)d_in[10];
  const float* Wr_gu  = (const float*)d_in[11];
  const int*   src_ug = (const int*)d_in[12];
  const int*   dst_ug = (const int*)d_in[13];
  const int*   src_gu = (const int*)d_in[14];
  const int*   dst_gu = (const int*)d_in[15];
  const int E = in_sizes[12];

  const int nch = (2 * E + CH - 1) / CH;      // stage-1 chunks
  const int n   = NBUCK * nch;                // scan length
  const int nb  = (n + 1023) / 1024;

  // workspace carve
  char* ws = (char*)d_ws;
  unsigned short* hu  = (unsigned short*)ws; ws += (size_t)NUSER * HDIM * 2;  // 25.6 MB
  unsigned short* hg  = (unsigned short*)ws; ws += (size_t)NGAME * HDIM * 2;  // 5.12 MB
  unsigned short* m   = (unsigned short*)ws; ws += (size_t)NTOT * HDIM * 2;   // 30.7 MB
  unsigned* hu8 = (unsigned*)ws; ws += (size_t)NUSER * HDIM;                   // 12.8 MB
  unsigned* esort = (unsigned*)ws; ws += (size_t)2 * E * 4;                    // 12.8 MB
  int* esrc  = (int*)ws; ws += (size_t)2 * E * 4;                              // 12.8 MB
  int* cnt   = (int*)ws; ws += (size_t)n * 4;                                  // ~0.75 MB
  int* off   = (int*)ws; ws += (size_t)(n + 1) * 4;
  int* offd  = (int*)ws; ws += (size_t)(NTOT + 1) * 4;                         // 0.48 MB
  int* bsum  = (int*)ws; ws += 2048 * 4;
  unsigned short* P_wu  = (unsigned short*)ws; ws += (size_t)2 * 8 * 64 * 8 * 2;  // 16 KB
  unsigned short* P_wg  = (unsigned short*)ws; ws += (size_t)4 * 8 * 64 * 8 * 2;  // 32 KB
  unsigned short* P_lug = (unsigned short*)ws; ws += (size_t)4 * 8 * 64 * 8 * 2;
  unsigned short* P_rug = (unsigned short*)ws; ws += (size_t)4 * 8 * 64 * 8 * 2;
  unsigned short* P_lgu = (unsigned short*)ws; ws += (size_t)4 * 8 * 64 * 8 * 2;
  unsigned short* P_rgu = (unsigned short*)ws; ws += (size_t)4 * 8 * 64 * 8 * 2;

  float* out_user = (float*)d_out;
  float* out_game = (float*)d_out + (size_t)NUSER * HDIM;

  // one-shot weight repack to MFMA fragment order (bf16)
  repack_kernel<<<dim3(8, 6), 256, 0, stream>>>(
      W_user, W_game, Wl_ug, Wr_ug, Wl_gu, Wr_gu,
      P_wu, P_wg, P_lug, P_rug, P_lgu, P_rgu);

  // input projections + relu (user proj also emits fp8 copy hu8)
  proj_mfma_kernel<64, true><<<(NUSER + 63) / 64, 256, 0, stream>>>(
      x_user, P_wu, b_user, hu, hu8, NUSER);
  proj_mfma_kernel<128, false><<<(NGAME + 63) / 64, 256, 0, stream>>>(
      x_game, P_wg, b_game, hg, nullptr, NGAME);

  // two-level counting sort (zero global atomics; scan3 folded into consumers)
  s1_hist_kernel<<<nch, 256, 0, stream>>>(dst_ug, dst_gu, cnt, E, nch);
  scan1_kernel<<<nb, 1024, 0, stream>>>(cnt, off, bsum, n);
  scan2_kernel<<<1, 1024, 0, stream>>>(bsum, off, nb, n);
  s1_scatter_kernel<<<nch, 256, 0, stream>>>(src_ug, dst_ug, src_gu, dst_gu, off, bsum, esort, E, nch);
  s2_csr_kernel<<<NBUCK, 256, 0, stream>>>(esort, off, bsum, offd, esrc, nch, n);

  // combined gather (means for both relations; one wave per row)
  gather_kernel<<<(NTOT * 64 + 255) / 256, 256, 0, stream>>>(hu8, hg, esrc, offd, m);

  // fused output projections
  out_mfma_fused_kernel<<<GBK + UBK, 256, 0, stream>>>(
      m, hg, hu, P_lug, bl_ug, P_rug, P_lgu, bl_gu, P_rgu, out_game, out_user);
}